// Round 3
// baseline (48.580 us; speedup 1.0000x reference)
//
#include <hip/hip_runtime.h>
#include <math.h>

#define D_IN_M   0.1f
#define D_OUT_M  1.0f

__device__ __forceinline__ float waveReduceSum(float v) {
    #pragma unroll
    for (int off = 32; off > 0; off >>= 1) v += __shfl_xor(v, off, 64);
    return v;
}

// Single fused kernel, R3: MSE uses contiguous 1536-float4 per-block chunks
// with 12 upfront independent loads; tc/orth moved AFTER the MSE loop.
__global__ __launch_bounds__(256, 2)
void cae_fused_kernel(const float4* __restrict__ x,
                      const float4* __restrict__ xh,
                      const int*    __restrict__ target,
                      const float*  __restrict__ z_in,
                      const float*  __restrict__ z_out,
                      const float*  __restrict__ center_arr,
                      float* __restrict__ out,
                      long n4, int B, int C, int L,
                      float invBD, float invB) {
    extern __shared__ float smc[];          // C*L normalized centers
    __shared__ float sred[4];
    __shared__ float sorth;

    const int tid  = threadIdx.x;
    const int wave = tid >> 6;
    const int lane = tid & 63;
    const int epl  = L >> 6;                // 2 for L=128

    // ---- stage + normalize centers (tiny: C*L = 5 KB) ----
    for (int c = wave; c < C; c += 4) {
        const float e0 = center_arr[c * L + lane * epl + 0];
        const float e1 = center_arr[c * L + lane * epl + 1];
        const float ss = waveReduceSum(e0 * e0 + e1 * e1);
        const float inv = rsqrtf(ss);
        smc[c * L + lane * epl + 0] = e0 * inv;
        smc[c * L + lane * epl + 1] = e1 * inv;
    }
    if (tid == 0) sorth = 0.f;
    __syncthreads();

    float v = 0.f;   // this thread's scaled contribution

    // ---- MSE: contiguous per-block chunk, 12 independent loads in flight ----
    {
        const long cpb = 6L * 256;          // float4s per block chunk (24 KB)
        float acc = 0.f;
        for (long i0 = (long)blockIdx.x * cpb; i0 < n4; i0 += (long)gridDim.x * cpb) {
            const long i = i0 + tid;
            if (i0 + cpb <= n4) {           // full chunk (always, for 4096x3072)
                const float4 a0 = x[i];
                const float4 a1 = x[i + 256];
                const float4 a2 = x[i + 512];
                const float4 a3 = x[i + 768];
                const float4 a4 = x[i + 1024];
                const float4 a5 = x[i + 1280];
                const float4 b0 = xh[i];
                const float4 b1 = xh[i + 256];
                const float4 b2 = xh[i + 512];
                const float4 b3 = xh[i + 768];
                const float4 b4 = xh[i + 1024];
                const float4 b5 = xh[i + 1280];
                float d;
                d = a0.x - b0.x; acc += d * d; d = a0.y - b0.y; acc += d * d;
                d = a0.z - b0.z; acc += d * d; d = a0.w - b0.w; acc += d * d;
                d = a1.x - b1.x; acc += d * d; d = a1.y - b1.y; acc += d * d;
                d = a1.z - b1.z; acc += d * d; d = a1.w - b1.w; acc += d * d;
                d = a2.x - b2.x; acc += d * d; d = a2.y - b2.y; acc += d * d;
                d = a2.z - b2.z; acc += d * d; d = a2.w - b2.w; acc += d * d;
                d = a3.x - b3.x; acc += d * d; d = a3.y - b3.y; acc += d * d;
                d = a3.z - b3.z; acc += d * d; d = a3.w - b3.w; acc += d * d;
                d = a4.x - b4.x; acc += d * d; d = a4.y - b4.y; acc += d * d;
                d = a4.z - b4.z; acc += d * d; d = a4.w - b4.w; acc += d * d;
                d = a5.x - b5.x; acc += d * d; d = a5.y - b5.y; acc += d * d;
                d = a5.z - b5.z; acc += d * d; d = a5.w - b5.w; acc += d * d;
            } else {                        // tail chunk
                for (long j = i; j < n4; j += 256) {
                    const float4 a = x[j], b = xh[j];
                    float d;
                    d = a.x - b.x; acc += d * d; d = a.y - b.y; acc += d * d;
                    d = a.z - b.z; acc += d * d; d = a.w - b.w; acc += d * d;
                }
            }
        }
        v = acc * invBD;
    }

    // ---- triplet-center + outlier: one wave per row, blocks [0, B/4) ----
    const int row = blockIdx.x * 4 + wave;
    if (row < B) {
        const float zi0 = z_in[row * L + lane * epl + 0];
        const float zi1 = z_in[row * L + lane * epl + 1];
        const int tgt = target[row];
        float pos = 0.f, neg = INFINITY;
        for (int c = 0; c < C; ++c) {
            const float d0 = zi0 - smc[c * L + lane * epl + 0];
            const float d1 = zi1 - smc[c * L + lane * epl + 1];
            const float d2 = waveReduceSum(d0 * d0 + d1 * d1);
            const float dist = sqrtf(d2);
            if (c == tgt) pos = dist;
            else          neg = fminf(neg, dist);
        }
        const float zo0 = z_out[row * L + lane * epl + 0];
        const float zo1 = z_out[row * L + lane * epl + 1];
        const float zo2 = waveReduceSum(zo0 * zo0 + zo1 * zo1);
        if (lane == 0) {
            const float tc = fmaxf(pos + D_IN_M - neg, 0.f);
            const float ol = fmaxf(D_OUT_M - sqrtf(zo2), 0.f);
            v += (tc + ol) * invB;
        }
    }

    // ---- orthogonality (block 0 only) ----
    if (blockIdx.x == 0) {
        float part = 0.f;
        for (int r = wave; r < C; r += 4) {
            const float a0 = smc[r * L + lane * epl + 0];
            const float a1 = smc[r * L + lane * epl + 1];
            for (int cc = 0; cc < C; ++cc) {
                const float d = waveReduceSum(
                    a0 * smc[cc * L + lane * epl + 0] +
                    a1 * smc[cc * L + lane * epl + 1]);
                const float t = d - (cc == r ? 1.f : 0.f);
                part += t * t;
            }
        }
        if (lane == 0) atomicAdd(&sorth, part);
    }

    // ---- block reduce + single atomicAdd ----
    v = waveReduceSum(v);
    if (lane == 0) sred[wave] = v;
    __syncthreads();
    if (tid == 0) {
        float s = sred[0] + sred[1] + sred[2] + sred[3];
        if (blockIdx.x == 0) s += sqrtf(sorth);
        atomicAdd(out, s);
    }
}

extern "C" void kernel_launch(void* const* d_in, const int* in_sizes, int n_in,
                              void* d_out, int out_size, void* d_ws, size_t ws_size,
                              hipStream_t stream) {
    const float* x          = (const float*)d_in[0];
    const float* x_hat      = (const float*)d_in[1];
    const int*   target     = (const int*)d_in[2];
    const float* z_in       = (const float*)d_in[3];
    const float* z_out      = (const float*)d_in[4];
    const float* center_arr = (const float*)d_in[5];
    float* out = (float*)d_out;

    const int B = in_sizes[2];
    const int D = in_sizes[0] / B;
    const int L = in_sizes[3] / B;
    const int C = in_sizes[5] / L;
    const long n4 = (long)B * D / 4;

    hipMemsetAsync(d_out, 0, sizeof(float), stream);

    cae_fused_kernel<<<2048, 256, C * L * sizeof(float), stream>>>(
        (const float4*)x, (const float4*)x_hat, target, z_in, z_out, center_arr,
        out, n4, B, C, L, 1.f / ((float)B * D), 1.f / (float)B);
}

// Round 4
// 28.389 us; speedup vs baseline: 1.7112x; 1.7112x over previous
//
#include <hip/hip_runtime.h>
#include <math.h>

#define D_IN_M   0.1f
#define D_OUT_M  1.0f
#define NBLK     2048

__device__ __forceinline__ float waveReduceSum(float v) {
    #pragma unroll
    for (int off = 32; off > 0; off >>= 1) v += __shfl_xor(v, off, 64);
    return v;
}

// R4: identical compute/memory structure to R3; ONLY the final reduction
// changed: per-block plain store into a private ws slot (64B-spaced),
// summed by a tiny second kernel. Tests the atomic-serialization theory.
__global__ __launch_bounds__(256, 2)
void cae_fused_kernel(const float4* __restrict__ x,
                      const float4* __restrict__ xh,
                      const int*    __restrict__ target,
                      const float*  __restrict__ z_in,
                      const float*  __restrict__ z_out,
                      const float*  __restrict__ center_arr,
                      float* __restrict__ ws, int slot_stride,
                      long n4, int B, int C, int L,
                      float invBD, float invB) {
    extern __shared__ float smc[];          // C*L normalized centers
    __shared__ float sred[4];
    __shared__ float sorth;

    const int tid  = threadIdx.x;
    const int wave = tid >> 6;
    const int lane = tid & 63;
    const int epl  = L >> 6;                // 2 for L=128

    // ---- stage + normalize centers (tiny: C*L = 5 KB) ----
    for (int c = wave; c < C; c += 4) {
        const float e0 = center_arr[c * L + lane * epl + 0];
        const float e1 = center_arr[c * L + lane * epl + 1];
        const float ss = waveReduceSum(e0 * e0 + e1 * e1);
        const float inv = rsqrtf(ss);
        smc[c * L + lane * epl + 0] = e0 * inv;
        smc[c * L + lane * epl + 1] = e1 * inv;
    }
    if (tid == 0) sorth = 0.f;
    __syncthreads();

    float v = 0.f;   // this thread's scaled contribution

    // ---- MSE: contiguous per-block chunk, 6x unrolled float4 pairs ----
    {
        const long cpb = 6L * 256;          // float4s per block chunk (24 KB)
        float acc = 0.f;
        for (long i0 = (long)blockIdx.x * cpb; i0 < n4; i0 += (long)gridDim.x * cpb) {
            const long i = i0 + tid;
            if (i0 + cpb <= n4) {           // full chunk (always, for 4096x3072)
                const float4 a0 = x[i];
                const float4 a1 = x[i + 256];
                const float4 a2 = x[i + 512];
                const float4 a3 = x[i + 768];
                const float4 a4 = x[i + 1024];
                const float4 a5 = x[i + 1280];
                const float4 b0 = xh[i];
                const float4 b1 = xh[i + 256];
                const float4 b2 = xh[i + 512];
                const float4 b3 = xh[i + 768];
                const float4 b4 = xh[i + 1024];
                const float4 b5 = xh[i + 1280];
                float d;
                d = a0.x - b0.x; acc += d * d; d = a0.y - b0.y; acc += d * d;
                d = a0.z - b0.z; acc += d * d; d = a0.w - b0.w; acc += d * d;
                d = a1.x - b1.x; acc += d * d; d = a1.y - b1.y; acc += d * d;
                d = a1.z - b1.z; acc += d * d; d = a1.w - b1.w; acc += d * d;
                d = a2.x - b2.x; acc += d * d; d = a2.y - b2.y; acc += d * d;
                d = a2.z - b2.z; acc += d * d; d = a2.w - b2.w; acc += d * d;
                d = a3.x - b3.x; acc += d * d; d = a3.y - b3.y; acc += d * d;
                d = a3.z - b3.z; acc += d * d; d = a3.w - b3.w; acc += d * d;
                d = a4.x - b4.x; acc += d * d; d = a4.y - b4.y; acc += d * d;
                d = a4.z - b4.z; acc += d * d; d = a4.w - b4.w; acc += d * d;
                d = a5.x - b5.x; acc += d * d; d = a5.y - b5.y; acc += d * d;
                d = a5.z - b5.z; acc += d * d; d = a5.w - b5.w; acc += d * d;
            } else {                        // tail chunk (not hit at 4096x3072)
                for (long j = i; j < n4; j += 256) {
                    const float4 a = x[j], b = xh[j];
                    float d;
                    d = a.x - b.x; acc += d * d; d = a.y - b.y; acc += d * d;
                    d = a.z - b.z; acc += d * d; d = a.w - b.w; acc += d * d;
                }
            }
        }
        v = acc * invBD;
    }

    // ---- triplet-center + outlier: one wave per row, blocks [0, B/4) ----
    const int row = blockIdx.x * 4 + wave;
    if (row < B) {
        const float zi0 = z_in[row * L + lane * epl + 0];
        const float zi1 = z_in[row * L + lane * epl + 1];
        const int tgt = target[row];
        float pos = 0.f, neg = INFINITY;
        for (int c = 0; c < C; ++c) {
            const float d0 = zi0 - smc[c * L + lane * epl + 0];
            const float d1 = zi1 - smc[c * L + lane * epl + 1];
            const float d2 = waveReduceSum(d0 * d0 + d1 * d1);
            const float dist = sqrtf(d2);
            if (c == tgt) pos = dist;
            else          neg = fminf(neg, dist);
        }
        const float zo0 = z_out[row * L + lane * epl + 0];
        const float zo1 = z_out[row * L + lane * epl + 1];
        const float zo2 = waveReduceSum(zo0 * zo0 + zo1 * zo1);
        if (lane == 0) {
            const float tc = fmaxf(pos + D_IN_M - neg, 0.f);
            const float ol = fmaxf(D_OUT_M - sqrtf(zo2), 0.f);
            v += (tc + ol) * invB;
        }
    }

    // ---- orthogonality (block 0 only) ----
    if (blockIdx.x == 0) {
        float part = 0.f;
        for (int r = wave; r < C; r += 4) {
            const float a0 = smc[r * L + lane * epl + 0];
            const float a1 = smc[r * L + lane * epl + 1];
            for (int cc = 0; cc < C; ++cc) {
                const float d = waveReduceSum(
                    a0 * smc[cc * L + lane * epl + 0] +
                    a1 * smc[cc * L + lane * epl + 1]);
                const float t = d - (cc == r ? 1.f : 0.f);
                part += t * t;
            }
        }
        if (lane == 0) atomicAdd(&sorth, part);
    }

    // ---- block reduce + PLAIN STORE to private slot (no atomics) ----
    v = waveReduceSum(v);
    if (lane == 0) sred[wave] = v;
    __syncthreads();
    if (tid == 0) {
        float s = sred[0] + sred[1] + sred[2] + sred[3];
        if (blockIdx.x == 0) s += sqrtf(sorth);
        ws[(long)blockIdx.x * slot_stride] = s;
    }
}

__global__ void reduce_kernel(const float* __restrict__ ws, int slot_stride,
                              float* __restrict__ out, int nblk) {
    const int tid = threadIdx.x;
    float s = 0.f;
    for (int i = tid; i < nblk; i += 256) s += ws[(long)i * slot_stride];
    s = waveReduceSum(s);
    __shared__ float sm[4];
    const int wave = tid >> 6, lane = tid & 63;
    if (lane == 0) sm[wave] = s;
    __syncthreads();
    if (tid == 0) out[0] = sm[0] + sm[1] + sm[2] + sm[3];
}

extern "C" void kernel_launch(void* const* d_in, const int* in_sizes, int n_in,
                              void* d_out, int out_size, void* d_ws, size_t ws_size,
                              hipStream_t stream) {
    const float* x          = (const float*)d_in[0];
    const float* x_hat      = (const float*)d_in[1];
    const int*   target     = (const int*)d_in[2];
    const float* z_in       = (const float*)d_in[3];
    const float* z_out      = (const float*)d_in[4];
    const float* center_arr = (const float*)d_in[5];
    float* out = (float*)d_out;
    float* ws  = (float*)d_ws;

    const int B = in_sizes[2];
    const int D = in_sizes[0] / B;
    const int L = in_sizes[3] / B;
    const int C = in_sizes[5] / L;
    const long n4 = (long)B * D / 4;

    // 64B-spaced slots if ws is big enough (avoids cross-XCD false sharing
    // entirely); contiguous otherwise (still correct via byte-enables).
    const int slot_stride = (ws_size >= (size_t)NBLK * 16 * sizeof(float)) ? 16 : 1;

    cae_fused_kernel<<<NBLK, 256, C * L * sizeof(float), stream>>>(
        (const float4*)x, (const float4*)x_hat, target, z_in, z_out, center_arr,
        ws, slot_stride, n4, B, C, L, 1.f / ((float)B * D), 1.f / (float)B);

    reduce_kernel<<<1, 256, 0, stream>>>(ws, slot_stride, out, NBLK);
}